// Round 17
// baseline (535.144 us; speedup 1.0000x reference)
//
#include <hip/hip_runtime.h>
#include <stdint.h>

typedef __bf16 bf16x8 __attribute__((ext_vector_type(8)));
typedef float f32x4 __attribute__((ext_vector_type(4)));
typedef float f32x16 __attribute__((ext_vector_type(16)));

#define S_LEN 2048
#define NKVH 8
#define HDIM 128
#define MROWS 4096        // B*S
#define LDQKV 6144        // fused QKV row stride
#define SCALE 0.08838834764831845f
#define C_LOG2 0.1275405707067851f   // SCALE * log2(e)
#define THR_RAW 62.7f                // 8 / C_LOG2
#define ROPE_L2 0.31143075889569023f // log2(1e6)/64

__device__ __forceinline__ unsigned short f2bf(float f) {
  unsigned u = __float_as_uint(f);
  u += 0x7FFFu + ((u >> 16) & 1u);
  return (unsigned short)(u >> 16);
}
__device__ __forceinline__ float bf2f(unsigned short h) {
  return __uint_as_float(((unsigned)h) << 16);
}

__device__ __forceinline__ void gload16(const unsigned short* g, unsigned short* l) {
  __builtin_amdgcn_global_load_lds(
      (__attribute__((address_space(1))) void*)(g),
      (__attribute__((address_space(3))) void*)(l), 16, 0, 0);
}

// ---------------- fused fp32->bf16 cast: hidden + Wq + Wk + Wv (one launch) ----------------
__global__ void cast4(const float4* __restrict__ s0, const float4* __restrict__ s1,
                      const float4* __restrict__ s2, const float4* __restrict__ s3,
                      ushort4* __restrict__ d0, ushort4* __restrict__ d1,
                      ushort4* __restrict__ d2, ushort4* __restrict__ d3) {
  const int b = blockIdx.x;
  const float4* s; ushort4* d; int lb;
  if (b < 1024)      { s = s0; d = d0; lb = b; }
  else if (b < 2048) { s = s1; d = d1; lb = b - 1024; }
  else if (b < 2304) { s = s2; d = d2; lb = b - 2048; }
  else               { s = s3; d = d3; lb = b - 2304; }
  int base = lb * 4096 + threadIdx.x;
#pragma unroll
  for (int i = 0; i < 16; i++) {
    float4 v = s[base + i * 256];
    ushort4 o;
    o.x = f2bf(v.x); o.y = f2bf(v.y); o.z = f2bf(v.z); o.w = f2bf(v.w);
    d[base + i * 256] = o;
  }
}

// ---------------- plain cast (Wo) ----------------
__global__ void cast_f32_bf16(const float4* __restrict__ in, ushort4* __restrict__ out, int n4) {
  int i = blockIdx.x * 256 + threadIdx.x;
  const int stride = gridDim.x * 256;
  for (; i < n4; i += stride) {
    float4 v = in[i];
    ushort4 o;
    o.x = f2bf(v.x); o.y = f2bf(v.y); o.z = f2bf(v.z); o.w = f2bf(v.w);
    out[i] = o;
  }
}

// ---------------- GEMM 256x256, BK=64, 8 waves, 8-phase schedule; XCD swizzle ----
template <int OUTF, int ROPE>
__global__ __launch_bounds__(512, 2)
void gemm256(const unsigned short* __restrict__ A,
             const unsigned short* __restrict__ Bw,
             const float* __restrict__ bias,
             void* __restrict__ C,
             const int* __restrict__ pos,
             int ldc, int K) {
  __shared__ unsigned short lds[8][8192];   // 128 KiB

  const int t = threadIdx.x;
  const int lane = t & 63;
  const int w = t >> 6;
  const int wr = w >> 2, wc = w & 3;           // 2 x 4 waves
  const int row16 = lane & 15, kgrp = lane >> 4;
  const int bid = blockIdx.x;
  const int swz = (bid & 7) * 32 + (bid >> 3);
  const int m0 = (swz >> 4) * 256, n0 = (swz & 15) * 256;

  const int riu = t >> 3;                           // 0..63
  const int col = (((t & 7) ^ (riu & 7)) << 3);     // pre-swizzled src col
  const int rB0 = (riu & 31) + ((riu >> 5) << 6);   // B qn0 row for load0
  const unsigned short* pA = A + (size_t)(m0 + riu) * K + col;
  const unsigned short* pB = Bw + (size_t)(n0 + rB0) * K + col;

#define STGU(SL, SRC)                                                       \
  {                                                                         \
    gload16((SRC), &lds[SL][t * 8]);                                        \
    gload16((SRC) + (size_t)128 * K, &lds[SL][4096 + t * 8]);               \
  }
#define RDA(SL)                                                             \
  _Pragma("unroll") for (int mi = 0; mi < 4; mi++)                          \
  _Pragma("unroll") for (int ks = 0; ks < 2; ks++)                          \
    afr[mi][ks] = *(const bf16x8*)(&lds[SL][0] + abase + mi * 1024 +        \
                                   ((((ks << 2) + kgrp) ^ sw) << 3));
#define RDB(SL, W)                                                          \
  _Pragma("unroll") for (int nj = 0; nj < 2; nj++)                          \
  _Pragma("unroll") for (int ks = 0; ks < 2; ks++)                          \
    bfr[W][nj][ks] = *(const bf16x8*)(&lds[SL][0] + bbase + nj * 1024 +     \
                                      ((((ks << 2) + kgrp) ^ sw) << 3));
#define MM(MO, NO, W)                                                       \
  __builtin_amdgcn_s_setprio(1);                                            \
  _Pragma("unroll") for (int mi = 0; mi < 4; mi++)                          \
  _Pragma("unroll") for (int nj = 0; nj < 2; nj++)                          \
  _Pragma("unroll") for (int ks = 0; ks < 2; ks++)                          \
    acc[(MO) + mi][(NO) + nj] = __builtin_amdgcn_mfma_f32_16x16x32_bf16(    \
        afr[mi][ks], bfr[W][nj][ks], acc[(MO) + mi][(NO) + nj], 0, 0, 0);   \
  __builtin_amdgcn_s_setprio(0);
#define BAR __builtin_amdgcn_s_barrier()

  const int sw = row16 & 7;
  const int abase = (wr * 64 + row16) * 64;
  const int bbase = (wc * 32 + row16) * 64;

  f32x4 acc[8][4];
#pragma unroll
  for (int i = 0; i < 8; i++)
#pragma unroll
    for (int j = 0; j < 4; j++) acc[i][j] = (f32x4){0.f, 0.f, 0.f, 0.f};

  bf16x8 afr[4][2], bfr[2][2][2];
  const int NT = K >> 6;
  const int NI = NT >> 1;

  STGU(0, pA);
  STGU(1, pB);
  STGU(2, pB + (size_t)32 * K);
  STGU(3, pA + (size_t)64 * K);
  STGU(4, pA + 64);
  STGU(5, pB + 64);
  STGU(6, pB + (size_t)32 * K + 64);
  asm volatile("s_waitcnt vmcnt(6)" ::: "memory");
  BAR;

  for (int I = 0; I < NI; ++I) {
    const size_t k1 = ((size_t)(2 * I + 1)) << 6;
    const size_t k2 = ((size_t)(2 * I + 2)) << 6;
    const size_t k3 = ((size_t)(2 * I + 3)) << 6;
    const bool s2 = (I + 1 < NI);

    RDA(0); RDB(1, 0);
    STGU(7, pA + (size_t)64 * K + k1);
    BAR;
    MM(0, 0, 0);
    BAR;
    RDB(2, 1);
    if (s2) STGU(0, pA + k2);
    BAR;
    MM(0, 2, 1);
    BAR;
    RDA(3);
    if (s2) STGU(1, pB + k2);
    BAR;
    MM(4, 2, 1);
    BAR;
    if (s2) {
      STGU(2, pB + (size_t)32 * K + k2);
      asm volatile("s_waitcnt vmcnt(6)" ::: "memory");
    } else {
      asm volatile("s_waitcnt vmcnt(0)" ::: "memory");
    }
    BAR;
    MM(4, 0, 0);
    BAR;
    RDA(4); RDB(5, 0);
    if (s2) STGU(3, pA + (size_t)64 * K + k2);
    BAR;
    MM(0, 0, 0);
    BAR;
    RDB(6, 1);
    if (s2) STGU(4, pA + k3);
    BAR;
    MM(0, 2, 1);
    BAR;
    RDA(7);
    if (s2) STGU(5, pB + k3);
    BAR;
    MM(4, 2, 1);
    BAR;
    if (s2) {
      STGU(6, pB + (size_t)32 * K + k3);
      asm volatile("s_waitcnt vmcnt(6)" ::: "memory");
    } else {
      asm volatile("s_waitcnt vmcnt(0)" ::: "memory");
    }
    BAR;
    MM(4, 0, 0);
    BAR;
  }
#undef STGU
#undef RDA
#undef RDB
#undef MM
#undef BAR

#pragma unroll
  for (int MI = 0; MI < 8; MI++) {
#pragma unroll
    for (int NJ = 0; NJ < 4; NJ++) {
      const int gr = m0 + wr * 128 + MI * 16 + kgrp * 4;
      const int gc = n0 + wc * 64 + NJ * 16 + row16;
      const float bv = bias[gc];
      if (ROPE) {
        const int hf = (gc & 127) >> 1;
        const float inv = exp2f(-(float)hf * ROPE_L2);
#pragma unroll
        for (int jj = 0; jj < 4; jj++) {
          float v = acc[MI][NJ][jj] + bv;
          float px = __shfl_xor(v, 1);
          float sn, cs;
          __sincosf((float)pos[gr + jj] * inv, &sn, &cs);
          float ov = (gc & 1) ? fmaf(v, cs, px * sn) : fmaf(v, cs, -px * sn);
          ((unsigned short*)C)[(size_t)(gr + jj) * ldc + gc] = f2bf(ov);
        }
      } else {
#pragma unroll
        for (int jj = 0; jj < 4; jj++) {
          float v = acc[MI][NJ][jj] + bv;
          if (OUTF) ((float*)C)[(size_t)(gr + jj) * ldc + gc] = v;
          else ((unsigned short*)C)[(size_t)(gr + jj) * ldc + gc] = f2bf(v);
        }
      }
    }
  }
}

// ---------------- GEMM 128x256, BK=64, 8 waves, 3-buffer ring; unified QKV (N=6144) ----
// 768 blocks = 3 exact dispatch rounds. XCD swizzle (bijective, 768%8==0):
// swz = (bid&7)*96 + bid>>3; mi = swz/24 (A-panel shared by 24 consecutive
// co-XCD blocks), ni = swz%24. RoPE applied for gc<5120 (Q and K heads; the
// 4096/5120 boundaries are 256-aligned so each block is region-uniform).
template <int OUTF, int ROPE>
__global__ __launch_bounds__(512, 2)
void gemm128(const unsigned short* __restrict__ A,
             const unsigned short* __restrict__ Bw,
             const float* __restrict__ bias,
             void* __restrict__ C,
             const int* __restrict__ pos,
             int ldc, int K) {
  __shared__ unsigned short lds[3 * 24576];   // 144 KiB

  const int t = threadIdx.x;
  const int lane = t & 63;
  const int w = t >> 6;
  const int wr = w >> 2, wc = w & 3;           // 2(M) x 4(N) waves -> 64x64 each
  const int row16 = lane & 15, kgrp = lane >> 4;
  const int bid = blockIdx.x;
  const int swz = (bid & 7) * 96 + (bid >> 3);
  const int m0 = (swz / 24) * 128, n0 = (swz % 24) * 256;

  const int riu = t >> 3;                           // 0..63
  const int col = (((t & 7) ^ (riu & 7)) << 3);     // pre-swizzled src col
  const unsigned short* pA = A + (size_t)(m0 + riu) * K + col;
  const unsigned short* pB = Bw + (size_t)(n0 + riu) * K + col;

#define STG6(bo_, kk_)                                                      \
  {                                                                         \
    gload16(pA + (kk_), &lds[(bo_) + t * 8]);                               \
    gload16(pA + (size_t)64 * K + (kk_), &lds[(bo_) + 4096 + t * 8]);       \
    gload16(pB + (kk_), &lds[(bo_) + 8192 + t * 8]);                        \
    gload16(pB + (size_t)64 * K + (kk_), &lds[(bo_) + 12288 + t * 8]);      \
    gload16(pB + (size_t)128 * K + (kk_), &lds[(bo_) + 16384 + t * 8]);     \
    gload16(pB + (size_t)192 * K + (kk_), &lds[(bo_) + 20480 + t * 8]);     \
  }

  const int sw = row16 & 7;
  const int abase = (wr * 64 + row16) * 64;           // within A unit
  const int bbase = 8192 + (wc * 64 + row16) * 64;    // within buffer (B at +8192)

  f32x4 acc[4][4];
#pragma unroll
  for (int i = 0; i < 4; i++)
#pragma unroll
    for (int j = 0; j < 4; j++) acc[i][j] = (f32x4){0.f, 0.f, 0.f, 0.f};

  bf16x8 afr[4][2], bfr[4][2];
  const int NT = K >> 6;

  STG6(0, 0);
  STG6(24576, 64);

  int rbc = 0;          // T%3 buffer offset index
  int rbs = 2;          // (T+2)%3
  for (int T = 0; T < NT; ++T) {
    if (T < NT - 1) { asm volatile("s_waitcnt vmcnt(6)\n\ts_barrier" ::: "memory"); }
    else            { asm volatile("s_waitcnt vmcnt(0)\n\ts_barrier" ::: "memory"); }
    if (T + 2 < NT) STG6(rbs * 24576, (size_t)(T + 2) << 6);
    const unsigned short* Lc = &lds[rbc * 24576];

#pragma unroll
    for (int mi = 0; mi < 4; mi++)
#pragma unroll
      for (int ks = 0; ks < 2; ks++)
        afr[mi][ks] = *(const bf16x8*)(Lc + abase + mi * 1024 + ((((ks << 2) + kgrp) ^ sw) << 3));
#pragma unroll
    for (int nj = 0; nj < 4; nj++)
#pragma unroll
      for (int ks = 0; ks < 2; ks++)
        bfr[nj][ks] = *(const bf16x8*)(Lc + bbase + nj * 1024 + ((((ks << 2) + kgrp) ^ sw) << 3));

    __builtin_amdgcn_s_setprio(1);
#pragma unroll
    for (int mi = 0; mi < 4; mi++)
#pragma unroll
      for (int nj = 0; nj < 4; nj++)
#pragma unroll
        for (int ks = 0; ks < 2; ks++)
          acc[mi][nj] = __builtin_amdgcn_mfma_f32_16x16x32_bf16(afr[mi][ks], bfr[nj][ks], acc[mi][nj], 0, 0, 0);
    __builtin_amdgcn_s_setprio(0);

    rbc++; if (rbc == 3) rbc = 0;
    rbs++; if (rbs == 3) rbs = 0;
  }
#undef STG6

#pragma unroll
  for (int MI = 0; MI < 4; MI++) {
#pragma unroll
    for (int NJ = 0; NJ < 4; NJ++) {
      const int gr = m0 + wr * 64 + MI * 16 + kgrp * 4;
      const int gc = n0 + wc * 64 + NJ * 16 + row16;
      const float bv = bias[gc];
      if (ROPE && gc < 5120) {          // Q + K heads (region-uniform per block)
        const int hf = (gc & 127) >> 1;
        const float inv = exp2f(-(float)hf * ROPE_L2);
#pragma unroll
        for (int jj = 0; jj < 4; jj++) {
          float v = acc[MI][NJ][jj] + bv;
          float px = __shfl_xor(v, 1);
          float sn, cs;
          __sincosf((float)pos[gr + jj] * inv, &sn, &cs);
          float ov = (gc & 1) ? fmaf(v, cs, px * sn) : fmaf(v, cs, -px * sn);
          ((unsigned short*)C)[(size_t)(gr + jj) * ldc + gc] = f2bf(ov);
        }
      } else {
#pragma unroll
        for (int jj = 0; jj < 4; jj++) {
          float v = acc[MI][NJ][jj] + bv;
          if (OUTF) ((float*)C)[(size_t)(gr + jj) * ldc + gc] = v;
          else ((unsigned short*)C)[(size_t)(gr + jj) * ldc + gc] = f2bf(v);
        }
      }
    }
  }
}

// ---------------- V transpose: V[m, n] (stride ldv) -> Vt[b*1024 + n][m % 2048] ----------------
__global__ void transpose_v(const unsigned short* __restrict__ V, int ldv,
                            unsigned short* __restrict__ Vt) {
  __shared__ unsigned short tile[32][40];
  const int t = threadIdx.x;
  const int n0 = blockIdx.x * 32;   // V col (0..1023)
  const int m0 = blockIdx.y * 32;   // V row (0..4095)
  const int r = t >> 3;
  const int c = (t & 7) << 2;
  const unsigned short* src = V + (size_t)(m0 + r) * ldv + n0 + c;
  ushort4 d = *(const ushort4*)src;
  tile[r][c] = d.x; tile[r][c + 1] = d.y; tile[r][c + 2] = d.z; tile[r][c + 3] = d.w;
  __syncthreads();
  const int b = m0 >> 11;
  unsigned short* dst = Vt + (size_t)(b * 1024 + n0 + r) * 2048 + (m0 & 2047) + c;
  ushort4 o;
  o.x = tile[c][r]; o.y = tile[c + 1][r]; o.z = tile[c + 2][r]; o.w = tile[c + 3][r];
  *(ushort4*)dst = o;
}

// ---------------- causal GQA flash attention, KVBLK=128, K-prefetch-under-softmax ----------------
// Single buffer; sK only read by QK^T, sV only by PV -> per tile:
//   vmcnt(8) [K(it) landed; V(it)+maybe K(it+1) in flight] -> bar -> QK^T
//   lgkmcnt(0)+bar [sK sealed] -> STAGE_K(it+1)  (hides K latency under softmax+PV)
//   softmax/P-conv -> vmcnt(8|0) [V(it) landed] -> bar -> PV
//   lgkmcnt(0)+bar [sV sealed] -> STAGE_V(it+1)
// Queue order keeps K always oldest-8: K issued mid-iter, V at end. Steady
// state 16 outstanding at loop top. Barriers uniform (compute predicated).
__global__ __launch_bounds__(256, 2)
void attn_kernel5(const unsigned short* __restrict__ QKV,
                  const unsigned short* __restrict__ Vt,
                  unsigned short* __restrict__ O) {
  __shared__ unsigned short sK[2 * 128 * 64];   // 32 KB
  __shared__ unsigned short sV[2 * 128 * 64];   // 32 KB

  const int t = threadIdx.x;
  const int lane = t & 63;
  const int w = t >> 6;                   // 0..3
  const int l31 = lane & 31;
  const int hi = lane >> 5;
  const int bid = blockIdx.x;
  const int g = bid >> 6, bh = bid & 63;
  const int qt = (g < 8) ? (15 - g) : (g - 8);
  const int b = bh >> 5, h = bh & 31;
  const int kh = h >> 2;                  // n_rep = 4 (repeat_interleave)
  const int q0 = qt << 7;                 // 128-row q-subtile
  const int qw = q0 + w * 32;
  const int qg = qw + l31;                // this lane's q row (softmax state owner)

  const int ntiles = qt + 1;              // KVBLK = 128
  const int myTiles = (qw + 159) >> 7;    // ceil((qw+32)/128)

  const int r5 = t >> 3;                  // 0..31
  const int psw = ((t & 7) ^ (r5 & 7)) << 3;    // pre-XOR'd col within 64-us half
  const unsigned short* Kp = QKV + (size_t)(b * S_LEN) * LDQKV + 4096 + kh * HDIM;
  const unsigned short* Vp = Vt + (size_t)(b * 1024 + kh * HDIM) * 2048;
  const unsigned short* KpA = Kp + (size_t)r5 * LDQKV + psw;
  const unsigned short* VpA = Vp + (size_t)r5 * 2048 + psw;

#define STAGE_K(kv0m)                                                          \
  {                                                                            \
    _Pragma("unroll")                                                          \
    for (int p = 0; p < 8; p++)                                                \
      gload16(KpA + (size_t)((kv0m) + ((p & 3) << 5)) * LDQKV + ((p >> 2) << 6), \
              &sK[p * 2048 + t * 8]);                                          \
  }
#define STAGE_V(kv0m)                                                          \
  {                                                                            \
    _Pragma("unroll")                                                          \
    for (int p = 0; p < 8; p++)                                                \
      gload16(VpA + (size_t)((p & 3) << 5) * 2048 + (kv0m) + ((p >> 2) << 6),  \
              &sV[p * 2048 + t * 8]);                                          \
  }

  bf16x8 qf[8];
  {
    const unsigned short* qb = QKV + (size_t)(b * S_LEN + qw + l31) * LDQKV + h * HDIM + hi * 8;
#pragma unroll
    for (int kd = 0; kd < 8; kd++) qf[kd] = *(const bf16x8*)(qb + kd * 16);
  }

  f32x16 o[4];
#pragma unroll
  for (int nt = 0; nt < 4; nt++)
#pragma unroll
    for (int r = 0; r < 16; r++) o[nt][r] = 0.f;
  float m = -1e30f, lsum = 0.f;

  const int rw7 = (l31 & 7) << 4;
  const int kswz = (hi << 4) ^ rw7;
  const int rbase = l31 << 6;             // row base within a 128x64 half

  STAGE_K(0);
  STAGE_V(0);
  for (int it = 0; it < ntiles; ++it) {
    asm volatile("s_waitcnt vmcnt(8)" ::: "memory");   // K(it) landed
    __builtin_amdgcn_s_barrier();

    const bool act = (it < myTiles);
    const bool more = (it + 1 < ntiles);
    bf16x8 pa[8];
    f32x16 st[4];

    if (act) {
#pragma unroll
      for (int r = 0; r < 16; r++) { st[0][r] = 0.f; st[1][r] = 0.f; st[2][r] = 0.f; st[3][r] = 0.f; }
      __builtin_amdgcn_s_setprio(1);
#pragma unroll
      for (int kd = 0; kd < 8; kd++) {
        const int koff = ((kd >> 2) << 13) + ((((kd & 3) << 5) ^ kswz) >> 1);
        bf16x8 k0 = *(const bf16x8*)(sK + koff + rbase);
        bf16x8 k1 = *(const bf16x8*)(sK + koff + rbase + 2048);
        bf16x8 k2 = *(const bf16x8*)(sK + koff + rbase + 4096);
        bf16x8 k3 = *(const bf16x8*)(sK + koff + rbase + 6144);
        st[0] = __builtin_amdgcn_mfma_f32_32x32x16_bf16(k0, qf[kd], st[0], 0, 0, 0);
        st[1] = __builtin_amdgcn_mfma_f32_32x32x16_bf16(k1, qf[kd], st[1], 0, 0, 0);
        st[2] = __builtin_amdgcn_mfma_f32_32x32x16_bf16(k2, qf[kd], st[2], 0, 0, 0);
        st[3] = __builtin_amdgcn_mfma_f32_32x32x16_bf16(k3, qf[kd], st[3], 0, 0, 0);
      }
      __builtin_amdgcn_s_setprio(0);
    }

    // seal sK (own ds_reads consumed; asm orders the following stage after)
    asm volatile("s_waitcnt lgkmcnt(0)" ::: "memory");
    __builtin_amdgcn_s_barrier();
    if (more) STAGE_K((it + 1) << 7);     // K(it+1) hides under softmax + PV

    if (act) {
      const int kv0 = it << 7;
      if (it == myTiles - 1) {
#pragma unroll
        for (int s2 = 0; s2 < 4; s2++)
#pragma unroll
          for (int r = 0; r < 16; r++) {
            const int kvg = kv0 + s2 * 32 + (r & 3) + 8 * (r >> 2) + 4 * hi;
            if (kvg > qg) st[s2][r] = -1e30f;
          }
      }

      float mx[8];
#pragma unroll
      for (int r = 0; r < 8; r++)
        mx[r] = fmaxf(fmaxf(fmaxf(st[0][r], st[0][r + 8]), fmaxf(st[1][r], st[1][r + 8])),
                      fmaxf(fmaxf(st[2][r], st[2][r + 8]), fmaxf(st[3][r], st[3][r + 8])));
#pragma unroll
      for (int d = 4; d >= 1; d >>= 1)
#pragma unroll
        for (int r = 0; r < d; r++) mx[r] = fmaxf(mx[r], mx[r + d]);
      float tmax = fmaxf(mx[0], __shfl_xor(mx[0], 32));

      if (!__all(tmax <= m + THR_RAW)) {
        const float mnew = fmaxf(m, tmax);
        const float corr = exp2f((m - mnew) * C_LOG2);
        lsum *= corr;
#pragma unroll
        for (int r = 0; r < 16; r++) {
          const int src = (r & 3) + 8 * (r >> 2) + 4 * hi;
          const float cr = __shfl(corr, src);
#pragma unroll
          for (int nt = 0; nt < 4; nt++) o[nt][r] *= cr;
        }
        m = mnew;
      }
      const float mC = m * C_LOG2;

#pragma unroll
      for (int s2 = 0; s2 < 4; s2++)
#pragma unroll
        for (int r = 0; r < 16; r++) st[s2][r] = exp2f(fmaf(st[s2][r], C_LOG2, -mC));
      float sm[8];
#pragma unroll
      for (int r = 0; r < 8; r++)
        sm[r] = ((st[0][r] + st[0][r + 8]) + (st[1][r] + st[1][r + 8])) +
                ((st[2][r] + st[2][r + 8]) + (st[3][r] + st[3][r + 8]));
#pragma unroll
      for (int d = 4; d >= 1; d >>= 1)
#pragma unroll
        for (int r = 0; r < d; r++) sm[r] += sm[r + d];
      float tsum = sm[0] + __shfl_xor(sm[0], 32);
      lsum += tsum;

#pragma unroll
      for (int s2 = 0; s2 < 4; s2++) {
        unsigned pw[8];
#pragma unroll
        for (int i = 0; i < 8; i++)
          asm("v_cvt_pk_bf16_f32 %0, %1, %2" : "=v"(pw[i]) : "v"(st[s2][2 * i]), "v"(st[s2][2 * i + 1]));
        const unsigned y0 = hi ? pw[0] : pw[2];
        const unsigned y1 = hi ? pw[1] : pw[3];
        const unsigned y2 = hi ? pw[4] : pw[6];
        const unsigned y3 = hi ? pw[5] : pw[7];
        const unsigned x0 = (unsigned)__shfl_xor((int)y0, 32);
        const unsigned x1 = (unsigned)__shfl_xor((int)y1, 32);
        const unsigned x2 = (unsigned)__shfl_xor((int)y2, 32);
        const unsigned x3 = (unsigned)__shfl_xor((int)y3, 32);
        union { unsigned u[4]; bf16x8 v; } u0, u1;
        u0.u[0] = hi ? x0 : pw[0];
        u0.u[1] = hi ? x1 : pw[1];
        u0.u[2] = hi ? pw[2] : x0;
        u0.u[3] = hi ? pw[3] : x1;
        u1.u[0] = hi ? x2 : pw[4];
        u1.u[1] = hi ? x3 : pw[5];
        u1.u[2] = hi ? pw[6] : x2;
        u1.u[3] = hi ? pw[7] : x3;
        pa[2 * s2] = u0.v; pa[2 * s2 + 1] = u1.v;
      }
    }

    if (more) { asm volatile("s_waitcnt vmcnt(8)" ::: "memory"); }   // V(it) landed (K(it+1) in flight)
    else      { asm volatile("s_waitcnt vmcnt(0)" ::: "memory"); }
    __builtin_amdgcn_s_barrier();

    if (act) {
      __builtin_amdgcn_s_setprio(1);
#pragma unroll
      for (int nt = 0; nt < 4; nt++) {
        const unsigned short* vr = sV + nt * 2048 + rbase;
#pragma unroll
        for (int ks = 0; ks < 8; ks++) {
          bf16x8 vb = *(const bf16x8*)(vr + ((ks >> 2) << 13) + ((((ks & 3) << 5) ^ kswz) >> 1));
          o[nt] = __builtin_amdgcn_mfma_f32_32x32x16_bf16(pa[ks], vb, o[nt], 0, 0, 0);
        }
      }
      __builtin_amdgcn_s_setprio(0);
    }

    // seal sV, then stage V(it+1)
    asm volatile("s_waitcnt lgkmcnt(0)" ::: "memory");
    __builtin_amdgcn_s_barrier();
    if (more) STAGE_V((it + 1) << 7);
  }

  const float linv = 1.0f / lsum;
#pragma unroll
  for (int r = 0; r < 16; r++) {
    const int qr = (r & 3) + 8 * (r >> 2) + 4 * hi;
    const float lr = __shfl(linv, qr);
    unsigned short* orow = O + (size_t)(b * S_LEN + qw + qr) * 4096 + h * HDIM + l31;
#pragma unroll
    for (int nt = 0; nt < 4; nt++) orow[nt * 32] = f2bf(o[nt][r] * lr);
  }
#undef STAGE_K
#undef STAGE_V
}

// ---------------- launch ----------------
extern "C" void kernel_launch(void* const* d_in, const int* in_sizes, int n_in,
                              void* d_out, int out_size, void* d_ws, size_t ws_size,
                              hipStream_t stream) {
  const float* hs = (const float*)d_in[0];
  const int*  pos = (const int*)d_in[1];
  const float* Wq = (const float*)d_in[2];
  const float* bq = (const float*)d_in[3];
  const float* Wk = (const float*)d_in[4];
  const float* bk = (const float*)d_in[5];
  const float* Wv = (const float*)d_in[6];
  const float* bv = (const float*)d_in[7];
  const float* Wo = (const float*)d_in[8];
  const float* bo = (const float*)d_in[9];
  float* out = (float*)d_out;

  char* ws = (char*)d_ws;
  unsigned short* hbf  = (unsigned short*)(ws);               // hidden bf16; later attn_out
  unsigned short* Wbuf = (unsigned short*)(ws + 33554432);    // Wqkv bf16 (contiguous 6144x4096); later Wo
  unsigned short* QKV  = (unsigned short*)(ws + 83886080);    // [4096][6144]
  unsigned short* Vtb  = (unsigned short*)(ws + 134217728);   // [2048][2048]
  float*          biasb= (float*)(ws + 142606336);            // 6144 floats

  // 1. fused casts (hidden + Wq + Wk + Wv, one launch)
  cast4<<<2560, 256, 0, stream>>>(
      (const float4*)hs, (const float4*)Wq, (const float4*)Wk, (const float4*)Wv,
      (ushort4*)hbf, (ushort4*)Wbuf, (ushort4*)(Wbuf + 16777216), (ushort4*)(Wbuf + 20971520));
  hipMemcpyAsync(biasb, bq, 4096 * 4, hipMemcpyDeviceToDevice, stream);
  hipMemcpyAsync(biasb + 4096, bk, 1024 * 4, hipMemcpyDeviceToDevice, stream);
  hipMemcpyAsync(biasb + 5120, bv, 1024 * 4, hipMemcpyDeviceToDevice, stream);

  // 2. unified QKV projection [4096 x 6144] + fused RoPE (gc<5120), one launch
  gemm128<0, 1><<<dim3(768), 512, 0, stream>>>(hbf, Wbuf, biasb, QKV, pos, LDQKV, 4096);

  // 3. Wo cast into Wbuf
  cast_f32_bf16<<<2048, 256, 0, stream>>>((const float4*)Wo, (ushort4*)Wbuf, 4194304);

  // 4. V transpose -> Vt[2048][2048]
  transpose_v<<<dim3(32, 128), 256, 0, stream>>>(QKV + 5120, LDQKV, Vtb);

  // 5. causal GQA flash attention (KVBLK=128, K-prefetch-under-softmax) -> hbf
  attn_kernel5<<<dim3(1024), 256, 0, stream>>>(QKV, Vtb, hbf);

  // 6. output projection -> fp32 d_out
  gemm256<1, 0><<<dim3(256), 512, 0, stream>>>(hbf, Wbuf, bo, out, nullptr, 4096, 4096);
}

// Round 18
// 502.458 us; speedup vs baseline: 1.0651x; 1.0651x over previous
//
#include <hip/hip_runtime.h>
#include <stdint.h>

typedef __bf16 bf16x8 __attribute__((ext_vector_type(8)));
typedef float f32x4 __attribute__((ext_vector_type(4)));
typedef float f32x16 __attribute__((ext_vector_type(16)));

#define S_LEN 2048
#define NKVH 8
#define HDIM 128
#define MROWS 4096        // B*S
#define LDQKV 6144        // fused QKV row stride
#define SCALE 0.08838834764831845f
#define C_LOG2 0.1275405707067851f   // SCALE * log2(e)
#define THR_RAW 62.7f                // 8 / C_LOG2
#define ROPE_L2 0.31143075889569023f // log2(1e6)/64

__device__ __forceinline__ unsigned short f2bf(float f) {
  unsigned u = __float_as_uint(f);
  u += 0x7FFFu + ((u >> 16) & 1u);
  return (unsigned short)(u >> 16);
}
__device__ __forceinline__ float bf2f(unsigned short h) {
  return __uint_as_float(((unsigned)h) << 16);
}

__device__ __forceinline__ void gload16(const unsigned short* g, unsigned short* l) {
  __builtin_amdgcn_global_load_lds(
      (__attribute__((address_space(1))) void*)(g),
      (__attribute__((address_space(3))) void*)(l), 16, 0, 0);
}

// ---------------- fused fp32->bf16 cast: hidden + Wq + Wk + Wv (one launch) ----------------
__global__ void cast4(const float4* __restrict__ s0, const float4* __restrict__ s1,
                      const float4* __restrict__ s2, const float4* __restrict__ s3,
                      ushort4* __restrict__ d0, ushort4* __restrict__ d1,
                      ushort4* __restrict__ d2, ushort4* __restrict__ d3) {
  const int b = blockIdx.x;
  const float4* s; ushort4* d; int lb;
  if (b < 1024)      { s = s0; d = d0; lb = b; }
  else if (b < 2048) { s = s1; d = d1; lb = b - 1024; }
  else if (b < 2304) { s = s2; d = d2; lb = b - 2048; }
  else               { s = s3; d = d3; lb = b - 2304; }
  int base = lb * 4096 + threadIdx.x;
#pragma unroll
  for (int i = 0; i < 16; i++) {
    float4 v = s[base + i * 256];
    ushort4 o;
    o.x = f2bf(v.x); o.y = f2bf(v.y); o.z = f2bf(v.z); o.w = f2bf(v.w);
    d[base + i * 256] = o;
  }
}

// ---------------- plain cast (Wo) ----------------
__global__ void cast_f32_bf16(const float4* __restrict__ in, ushort4* __restrict__ out, int n4) {
  int i = blockIdx.x * 256 + threadIdx.x;
  const int stride = gridDim.x * 256;
  for (; i < n4; i += stride) {
    float4 v = in[i];
    ushort4 o;
    o.x = f2bf(v.x); o.y = f2bf(v.y); o.z = f2bf(v.z); o.w = f2bf(v.w);
    out[i] = o;
  }
}

// ---------------- GEMM 256x256, BK=64, 8 waves, 8-phase schedule; XCD swizzle ----
template <int OUTF, int ROPE>
__global__ __launch_bounds__(512, 2)
void gemm256(const unsigned short* __restrict__ A,
             const unsigned short* __restrict__ Bw,
             const float* __restrict__ bias,
             void* __restrict__ C,
             const int* __restrict__ pos,
             int ldc, int K) {
  __shared__ unsigned short lds[8][8192];   // 128 KiB

  const int t = threadIdx.x;
  const int lane = t & 63;
  const int w = t >> 6;
  const int wr = w >> 2, wc = w & 3;           // 2 x 4 waves
  const int row16 = lane & 15, kgrp = lane >> 4;
  const int bid = blockIdx.x;
  const int swz = (bid & 7) * 32 + (bid >> 3);
  const int m0 = (swz >> 4) * 256, n0 = (swz & 15) * 256;

  const int riu = t >> 3;                           // 0..63
  const int col = (((t & 7) ^ (riu & 7)) << 3);     // pre-swizzled src col
  const int rB0 = (riu & 31) + ((riu >> 5) << 6);   // B qn0 row for load0
  const unsigned short* pA = A + (size_t)(m0 + riu) * K + col;
  const unsigned short* pB = Bw + (size_t)(n0 + rB0) * K + col;

#define STGU(SL, SRC)                                                       \
  {                                                                         \
    gload16((SRC), &lds[SL][t * 8]);                                        \
    gload16((SRC) + (size_t)128 * K, &lds[SL][4096 + t * 8]);               \
  }
#define RDA(SL)                                                             \
  _Pragma("unroll") for (int mi = 0; mi < 4; mi++)                          \
  _Pragma("unroll") for (int ks = 0; ks < 2; ks++)                          \
    afr[mi][ks] = *(const bf16x8*)(&lds[SL][0] + abase + mi * 1024 +        \
                                   ((((ks << 2) + kgrp) ^ sw) << 3));
#define RDB(SL, W)                                                          \
  _Pragma("unroll") for (int nj = 0; nj < 2; nj++)                          \
  _Pragma("unroll") for (int ks = 0; ks < 2; ks++)                          \
    bfr[W][nj][ks] = *(const bf16x8*)(&lds[SL][0] + bbase + nj * 1024 +     \
                                      ((((ks << 2) + kgrp) ^ sw) << 3));
#define MM(MO, NO, W)                                                       \
  __builtin_amdgcn_s_setprio(1);                                            \
  _Pragma("unroll") for (int mi = 0; mi < 4; mi++)                          \
  _Pragma("unroll") for (int nj = 0; nj < 2; nj++)                          \
  _Pragma("unroll") for (int ks = 0; ks < 2; ks++)                          \
    acc[(MO) + mi][(NO) + nj] = __builtin_amdgcn_mfma_f32_16x16x32_bf16(    \
        afr[mi][ks], bfr[W][nj][ks], acc[(MO) + mi][(NO) + nj], 0, 0, 0);   \
  __builtin_amdgcn_s_setprio(0);
#define BAR __builtin_amdgcn_s_barrier()

  const int sw = row16 & 7;
  const int abase = (wr * 64 + row16) * 64;
  const int bbase = (wc * 32 + row16) * 64;

  f32x4 acc[8][4];
#pragma unroll
  for (int i = 0; i < 8; i++)
#pragma unroll
    for (int j = 0; j < 4; j++) acc[i][j] = (f32x4){0.f, 0.f, 0.f, 0.f};

  bf16x8 afr[4][2], bfr[2][2][2];
  const int NT = K >> 6;
  const int NI = NT >> 1;

  STGU(0, pA);
  STGU(1, pB);
  STGU(2, pB + (size_t)32 * K);
  STGU(3, pA + (size_t)64 * K);
  STGU(4, pA + 64);
  STGU(5, pB + 64);
  STGU(6, pB + (size_t)32 * K + 64);
  asm volatile("s_waitcnt vmcnt(6)" ::: "memory");
  BAR;

  for (int I = 0; I < NI; ++I) {
    const size_t k1 = ((size_t)(2 * I + 1)) << 6;
    const size_t k2 = ((size_t)(2 * I + 2)) << 6;
    const size_t k3 = ((size_t)(2 * I + 3)) << 6;
    const bool s2 = (I + 1 < NI);

    RDA(0); RDB(1, 0);
    STGU(7, pA + (size_t)64 * K + k1);
    BAR;
    MM(0, 0, 0);
    BAR;
    RDB(2, 1);
    if (s2) STGU(0, pA + k2);
    BAR;
    MM(0, 2, 1);
    BAR;
    RDA(3);
    if (s2) STGU(1, pB + k2);
    BAR;
    MM(4, 2, 1);
    BAR;
    if (s2) {
      STGU(2, pB + (size_t)32 * K + k2);
      asm volatile("s_waitcnt vmcnt(6)" ::: "memory");
    } else {
      asm volatile("s_waitcnt vmcnt(0)" ::: "memory");
    }
    BAR;
    MM(4, 0, 0);
    BAR;
    RDA(4); RDB(5, 0);
    if (s2) STGU(3, pA + (size_t)64 * K + k2);
    BAR;
    MM(0, 0, 0);
    BAR;
    RDB(6, 1);
    if (s2) STGU(4, pA + k3);
    BAR;
    MM(0, 2, 1);
    BAR;
    RDA(7);
    if (s2) STGU(5, pB + k3);
    BAR;
    MM(4, 2, 1);
    BAR;
    if (s2) {
      STGU(6, pB + (size_t)32 * K + k3);
      asm volatile("s_waitcnt vmcnt(6)" ::: "memory");
    } else {
      asm volatile("s_waitcnt vmcnt(0)" ::: "memory");
    }
    BAR;
    MM(4, 0, 0);
    BAR;
  }
#undef STGU
#undef RDA
#undef RDB
#undef MM
#undef BAR

#pragma unroll
  for (int MI = 0; MI < 8; MI++) {
#pragma unroll
    for (int NJ = 0; NJ < 4; NJ++) {
      const int gr = m0 + wr * 128 + MI * 16 + kgrp * 4;
      const int gc = n0 + wc * 64 + NJ * 16 + row16;
      const float bv = bias[gc];
      if (ROPE) {
        const int hf = (gc & 127) >> 1;
        const float inv = exp2f(-(float)hf * ROPE_L2);
#pragma unroll
        for (int jj = 0; jj < 4; jj++) {
          float v = acc[MI][NJ][jj] + bv;
          float px = __shfl_xor(v, 1);
          float sn, cs;
          __sincosf((float)pos[gr + jj] * inv, &sn, &cs);
          float ov = (gc & 1) ? fmaf(v, cs, px * sn) : fmaf(v, cs, -px * sn);
          ((unsigned short*)C)[(size_t)(gr + jj) * ldc + gc] = f2bf(ov);
        }
      } else {
#pragma unroll
        for (int jj = 0; jj < 4; jj++) {
          float v = acc[MI][NJ][jj] + bv;
          if (OUTF) ((float*)C)[(size_t)(gr + jj) * ldc + gc] = v;
          else ((unsigned short*)C)[(size_t)(gr + jj) * ldc + gc] = f2bf(v);
        }
      }
    }
  }
}

// ---------------- GEMM 128x256, BK=64, 8 waves, 3-buffer ring; fused K-RoPE; XCD swizzle ----
template <int OUTF, int ROPE>
__global__ __launch_bounds__(512, 2)
void gemm128(const unsigned short* __restrict__ A,
             const unsigned short* __restrict__ Bw,
             const float* __restrict__ bias,
             void* __restrict__ C,
             const int* __restrict__ pos,
             int ldc, int K) {
  __shared__ unsigned short lds[3 * 24576];   // 144 KiB

  const int t = threadIdx.x;
  const int lane = t & 63;
  const int w = t >> 6;
  const int wr = w >> 2, wc = w & 3;           // 2(M) x 4(N) waves -> 64x64 each
  const int row16 = lane & 15, kgrp = lane >> 4;
  const int bid = blockIdx.x;
  const int swz = (bid & 7) * 32 + (bid >> 3);
  const int m0 = (swz >> 3) * 128, n0 = (swz & 7) * 256;

  const int riu = t >> 3;                           // 0..63
  const int col = (((t & 7) ^ (riu & 7)) << 3);     // pre-swizzled src col
  const unsigned short* pA = A + (size_t)(m0 + riu) * K + col;
  const unsigned short* pB = Bw + (size_t)(n0 + riu) * K + col;

#define STG6(bo_, kk_)                                                      \
  {                                                                         \
    gload16(pA + (kk_), &lds[(bo_) + t * 8]);                               \
    gload16(pA + (size_t)64 * K + (kk_), &lds[(bo_) + 4096 + t * 8]);       \
    gload16(pB + (kk_), &lds[(bo_) + 8192 + t * 8]);                        \
    gload16(pB + (size_t)64 * K + (kk_), &lds[(bo_) + 12288 + t * 8]);      \
    gload16(pB + (size_t)128 * K + (kk_), &lds[(bo_) + 16384 + t * 8]);     \
    gload16(pB + (size_t)192 * K + (kk_), &lds[(bo_) + 20480 + t * 8]);     \
  }

  const int sw = row16 & 7;
  const int abase = (wr * 64 + row16) * 64;           // within A unit
  const int bbase = 8192 + (wc * 64 + row16) * 64;    // within buffer (B at +8192)

  f32x4 acc[4][4];
#pragma unroll
  for (int i = 0; i < 4; i++)
#pragma unroll
    for (int j = 0; j < 4; j++) acc[i][j] = (f32x4){0.f, 0.f, 0.f, 0.f};

  bf16x8 afr[4][2], bfr[4][2];
  const int NT = K >> 6;

  STG6(0, 0);
  STG6(24576, 64);

  int rbc = 0;          // T%3 buffer offset index
  int rbs = 2;          // (T+2)%3
  for (int T = 0; T < NT; ++T) {
    if (T < NT - 1) { asm volatile("s_waitcnt vmcnt(6)\n\ts_barrier" ::: "memory"); }
    else            { asm volatile("s_waitcnt vmcnt(0)\n\ts_barrier" ::: "memory"); }
    if (T + 2 < NT) STG6(rbs * 24576, (size_t)(T + 2) << 6);
    const unsigned short* Lc = &lds[rbc * 24576];

#pragma unroll
    for (int mi = 0; mi < 4; mi++)
#pragma unroll
      for (int ks = 0; ks < 2; ks++)
        afr[mi][ks] = *(const bf16x8*)(Lc + abase + mi * 1024 + ((((ks << 2) + kgrp) ^ sw) << 3));
#pragma unroll
    for (int nj = 0; nj < 4; nj++)
#pragma unroll
      for (int ks = 0; ks < 2; ks++)
        bfr[nj][ks] = *(const bf16x8*)(Lc + bbase + nj * 1024 + ((((ks << 2) + kgrp) ^ sw) << 3));

    __builtin_amdgcn_s_setprio(1);
#pragma unroll
    for (int mi = 0; mi < 4; mi++)
#pragma unroll
      for (int nj = 0; nj < 4; nj++)
#pragma unroll
        for (int ks = 0; ks < 2; ks++)
          acc[mi][nj] = __builtin_amdgcn_mfma_f32_16x16x32_bf16(afr[mi][ks], bfr[nj][ks], acc[mi][nj], 0, 0, 0);
    __builtin_amdgcn_s_setprio(0);

    rbc++; if (rbc == 3) rbc = 0;
    rbs++; if (rbs == 3) rbs = 0;
  }
#undef STG6

#pragma unroll
  for (int MI = 0; MI < 4; MI++) {
#pragma unroll
    for (int NJ = 0; NJ < 4; NJ++) {
      const int gr = m0 + wr * 64 + MI * 16 + kgrp * 4;
      const int gc = n0 + wc * 64 + NJ * 16 + row16;
      const float bv = bias[gc];
      if (ROPE && gc < 1024) {          // K region (uniform per block: 256 | 1024)
        const int hf = (gc & 127) >> 1;
        const float inv = exp2f(-(float)hf * ROPE_L2);
#pragma unroll
        for (int jj = 0; jj < 4; jj++) {
          float v = acc[MI][NJ][jj] + bv;
          float px = __shfl_xor(v, 1);
          float sn, cs;
          __sincosf((float)pos[gr + jj] * inv, &sn, &cs);
          float ov = (gc & 1) ? fmaf(v, cs, px * sn) : fmaf(v, cs, -px * sn);
          ((unsigned short*)C)[(size_t)(gr + jj) * ldc + gc] = f2bf(ov);
        }
      } else {
#pragma unroll
        for (int jj = 0; jj < 4; jj++) {
          float v = acc[MI][NJ][jj] + bv;
          if (OUTF) ((float*)C)[(size_t)(gr + jj) * ldc + gc] = v;
          else ((unsigned short*)C)[(size_t)(gr + jj) * ldc + gc] = f2bf(v);
        }
      }
    }
  }
}

// ---------------- V transpose: V[m, n] (stride ldv) -> Vt[b*1024 + n][m % 2048] ----------------
__global__ void transpose_v(const unsigned short* __restrict__ V, int ldv,
                            unsigned short* __restrict__ Vt) {
  __shared__ unsigned short tile[32][40];
  const int t = threadIdx.x;
  const int n0 = blockIdx.x * 32;   // V col (0..1023)
  const int m0 = blockIdx.y * 32;   // V row (0..4095)
  const int r = t >> 3;
  const int c = (t & 7) << 2;
  const unsigned short* src = V + (size_t)(m0 + r) * ldv + n0 + c;
  ushort4 d = *(const ushort4*)src;
  tile[r][c] = d.x; tile[r][c + 1] = d.y; tile[r][c + 2] = d.z; tile[r][c + 3] = d.w;
  __syncthreads();
  const int b = m0 >> 11;
  unsigned short* dst = Vt + (size_t)(b * 1024 + n0 + r) * 2048 + (m0 & 2047) + c;
  ushort4 o;
  o.x = tile[c][r]; o.y = tile[c + 1][r]; o.z = tile[c + 2][r]; o.w = tile[c + 3][r];
  *(ushort4*)dst = o;
}

// ---------------- causal GQA flash attention, KVBLK=128, K-prefetch-under-softmax ----------------
__global__ __launch_bounds__(256, 2)
void attn_kernel5(const unsigned short* __restrict__ QKV,
                  const unsigned short* __restrict__ Vt,
                  unsigned short* __restrict__ O) {
  __shared__ unsigned short sK[2 * 128 * 64];   // 32 KB
  __shared__ unsigned short sV[2 * 128 * 64];   // 32 KB

  const int t = threadIdx.x;
  const int lane = t & 63;
  const int w = t >> 6;                   // 0..3
  const int l31 = lane & 31;
  const int hi = lane >> 5;
  const int bid = blockIdx.x;
  const int g = bid >> 6, bh = bid & 63;
  const int qt = (g < 8) ? (15 - g) : (g - 8);
  const int b = bh >> 5, h = bh & 31;
  const int kh = h >> 2;                  // n_rep = 4 (repeat_interleave)
  const int q0 = qt << 7;                 // 128-row q-subtile
  const int qw = q0 + w * 32;
  const int qg = qw + l31;                // this lane's q row (softmax state owner)

  const int ntiles = qt + 1;              // KVBLK = 128
  const int myTiles = (qw + 159) >> 7;    // ceil((qw+32)/128)

  const int r5 = t >> 3;                  // 0..31
  const int psw = ((t & 7) ^ (r5 & 7)) << 3;    // pre-XOR'd col within 64-us half
  const unsigned short* Kp = QKV + (size_t)(b * S_LEN) * LDQKV + 4096 + kh * HDIM;
  const unsigned short* Vp = Vt + (size_t)(b * 1024 + kh * HDIM) * 2048;
  const unsigned short* KpA = Kp + (size_t)r5 * LDQKV + psw;
  const unsigned short* VpA = Vp + (size_t)r5 * 2048 + psw;

#define STAGE_K(kv0m)                                                          \
  {                                                                            \
    _Pragma("unroll")                                                          \
    for (int p = 0; p < 8; p++)                                                \
      gload16(KpA + (size_t)((kv0m) + ((p & 3) << 5)) * LDQKV + ((p >> 2) << 6), \
              &sK[p * 2048 + t * 8]);                                          \
  }
#define STAGE_V(kv0m)                                                          \
  {                                                                            \
    _Pragma("unroll")                                                          \
    for (int p = 0; p < 8; p++)                                                \
      gload16(VpA + (size_t)((p & 3) << 5) * 2048 + (kv0m) + ((p >> 2) << 6),  \
              &sV[p * 2048 + t * 8]);                                          \
  }

  bf16x8 qf[8];
  {
    const unsigned short* qb = QKV + (size_t)(b * S_LEN + qw + l31) * LDQKV + h * HDIM + hi * 8;
#pragma unroll
    for (int kd = 0; kd < 8; kd++) qf[kd] = *(const bf16x8*)(qb + kd * 16);
  }

  f32x16 o[4];
#pragma unroll
  for (int nt = 0; nt < 4; nt++)
#pragma unroll
    for (int r = 0; r < 16; r++) o[nt][r] = 0.f;
  float m = -1e30f, lsum = 0.f;

  const int rw7 = (l31 & 7) << 4;
  const int kswz = (hi << 4) ^ rw7;
  const int rbase = l31 << 6;             // row base within a 128x64 half

  STAGE_K(0);
  STAGE_V(0);
  for (int it = 0; it < ntiles; ++it) {
    asm volatile("s_waitcnt vmcnt(8)" ::: "memory");   // K(it) landed
    __builtin_amdgcn_s_barrier();

    const bool act = (it < myTiles);
    const bool more = (it + 1 < ntiles);
    bf16x8 pa[8];
    f32x16 st[4];

    if (act) {
#pragma unroll
      for (int r = 0; r < 16; r++) { st[0][r] = 0.f; st[1][r] = 0.f; st[2][r] = 0.f; st[3][r] = 0.f; }
      __builtin_amdgcn_s_setprio(1);
#pragma unroll
      for (int kd = 0; kd < 8; kd++) {
        const int koff = ((kd >> 2) << 13) + ((((kd & 3) << 5) ^ kswz) >> 1);
        bf16x8 k0 = *(const bf16x8*)(sK + koff + rbase);
        bf16x8 k1 = *(const bf16x8*)(sK + koff + rbase + 2048);
        bf16x8 k2 = *(const bf16x8*)(sK + koff + rbase + 4096);
        bf16x8 k3 = *(const bf16x8*)(sK + koff + rbase + 6144);
        st[0] = __builtin_amdgcn_mfma_f32_32x32x16_bf16(k0, qf[kd], st[0], 0, 0, 0);
        st[1] = __builtin_amdgcn_mfma_f32_32x32x16_bf16(k1, qf[kd], st[1], 0, 0, 0);
        st[2] = __builtin_amdgcn_mfma_f32_32x32x16_bf16(k2, qf[kd], st[2], 0, 0, 0);
        st[3] = __builtin_amdgcn_mfma_f32_32x32x16_bf16(k3, qf[kd], st[3], 0, 0, 0);
      }
      __builtin_amdgcn_s_setprio(0);
    }

    // seal sK (own ds_reads consumed; asm orders the following stage after)
    asm volatile("s_waitcnt lgkmcnt(0)" ::: "memory");
    __builtin_amdgcn_s_barrier();
    if (more) STAGE_K((it + 1) << 7);     // K(it+1) hides under softmax + PV

    if (act) {
      const int kv0 = it << 7;
      if (it == myTiles - 1) {
#pragma unroll
        for (int s2 = 0; s2 < 4; s2++)
#pragma unroll
          for (int r = 0; r < 16; r++) {
            const int kvg = kv0 + s2 * 32 + (r & 3) + 8 * (r >> 2) + 4 * hi;
            if (kvg > qg) st[s2][r] = -1e30f;
          }
      }

      float mx[8];
#pragma unroll
      for (int r = 0; r < 8; r++)
        mx[r] = fmaxf(fmaxf(fmaxf(st[0][r], st[0][r + 8]), fmaxf(st[1][r], st[1][r + 8])),
                      fmaxf(fmaxf(st[2][r], st[2][r + 8]), fmaxf(st[3][r], st[3][r + 8])));
#pragma unroll
      for (int d = 4; d >= 1; d >>= 1)
#pragma unroll
        for (int r = 0; r < d; r++) mx[r] = fmaxf(mx[r], mx[r + d]);
      float tmax = fmaxf(mx[0], __shfl_xor(mx[0], 32));

      if (!__all(tmax <= m + THR_RAW)) {
        const float mnew = fmaxf(m, tmax);
        const float corr = exp2f((m - mnew) * C_LOG2);
        lsum *= corr;
#pragma unroll
        for (int r = 0; r < 16; r++) {
          const int src = (r & 3) + 8 * (r >> 2) + 4 * hi;
          const float cr = __shfl(corr, src);
#pragma unroll
          for (int nt = 0; nt < 4; nt++) o[nt][r] *= cr;
        }
        m = mnew;
      }
      const float mC = m * C_LOG2;

#pragma unroll
      for (int s2 = 0; s2 < 4; s2++)
#pragma unroll
        for (int r = 0; r < 16; r++) st[s2][r] = exp2f(fmaf(st[s2][r], C_LOG2, -mC));
      float sm[8];
#pragma unroll
      for (int r = 0; r < 8; r++)
        sm[r] = ((st[0][r] + st[0][r + 8]) + (st[1][r] + st[1][r + 8])) +
                ((st[2][r] + st[2][r + 8]) + (st[3][r] + st[3][r + 8]));
#pragma unroll
      for (int d = 4; d >= 1; d >>= 1)
#pragma unroll
        for (int r = 0; r < d; r++) sm[r] += sm[r + d];
      float tsum = sm[0] + __shfl_xor(sm[0], 32);
      lsum += tsum;

#pragma unroll
      for (int s2 = 0; s2 < 4; s2++) {
        unsigned pw[8];
#pragma unroll
        for (int i = 0; i < 8; i++)
          asm("v_cvt_pk_bf16_f32 %0, %1, %2" : "=v"(pw[i]) : "v"(st[s2][2 * i]), "v"(st[s2][2 * i + 1]));
        const unsigned y0 = hi ? pw[0] : pw[2];
        const unsigned y1 = hi ? pw[1] : pw[3];
        const unsigned y2 = hi ? pw[4] : pw[6];
        const unsigned y3 = hi ? pw[5] : pw[7];
        const unsigned x0 = (unsigned)__shfl_xor((int)y0, 32);
        const unsigned x1 = (unsigned)__shfl_xor((int)y1, 32);
        const unsigned x2 = (unsigned)__shfl_xor((int)y2, 32);
        const unsigned x3 = (unsigned)__shfl_xor((int)y3, 32);
        union { unsigned u[4]; bf16x8 v; } u0, u1;
        u0.u[0] = hi ? x0 : pw[0];
        u0.u[1] = hi ? x1 : pw[1];
        u0.u[2] = hi ? pw[2] : x0;
        u0.u[3] = hi ? pw[3] : x1;
        u1.u[0] = hi ? x2 : pw[4];
        u1.u[1] = hi ? x3 : pw[5];
        u1.u[2] = hi ? pw[6] : x2;
        u1.u[3] = hi ? pw[7] : x3;
        pa[2 * s2] = u0.v; pa[2 * s2 + 1] = u1.v;
      }
    }

    if (more) { asm volatile("s_waitcnt vmcnt(8)" ::: "memory"); }   // V(it) landed (K(it+1) in flight)
    else      { asm volatile("s_waitcnt vmcnt(0)" ::: "memory"); }
    __builtin_amdgcn_s_barrier();

    if (act) {
      __builtin_amdgcn_s_setprio(1);
#pragma unroll
      for (int nt = 0; nt < 4; nt++) {
        const unsigned short* vr = sV + nt * 2048 + rbase;
#pragma unroll
        for (int ks = 0; ks < 8; ks++) {
          bf16x8 vb = *(const bf16x8*)(vr + ((ks >> 2) << 13) + ((((ks & 3) << 5) ^ kswz) >> 1));
          o[nt] = __builtin_amdgcn_mfma_f32_32x32x16_bf16(pa[ks], vb, o[nt], 0, 0, 0);
        }
      }
      __builtin_amdgcn_s_setprio(0);
    }

    // seal sV, then stage V(it+1)
    asm volatile("s_waitcnt lgkmcnt(0)" ::: "memory");
    __builtin_amdgcn_s_barrier();
    if (more) STAGE_V((it + 1) << 7);
  }

  const float linv = 1.0f / lsum;
#pragma unroll
  for (int r = 0; r < 16; r++) {
    const int qr = (r & 3) + 8 * (r >> 2) + 4 * hi;
    const float lr = __shfl(linv, qr);
    unsigned short* orow = O + (size_t)(b * S_LEN + qw + qr) * 4096 + h * HDIM + l31;
#pragma unroll
    for (int nt = 0; nt < 4; nt++) orow[nt * 32] = f2bf(o[nt][r] * lr);
  }
#undef STAGE_K
#undef STAGE_V
}

// ---------------- launch ----------------
extern "C" void kernel_launch(void* const* d_in, const int* in_sizes, int n_in,
                              void* d_out, int out_size, void* d_ws, size_t ws_size,
                              hipStream_t stream) {
  const float* hs = (const float*)d_in[0];
  const int*  pos = (const int*)d_in[1];
  const float* Wq = (const float*)d_in[2];
  const float* bq = (const float*)d_in[3];
  const float* Wk = (const float*)d_in[4];
  const float* bk = (const float*)d_in[5];
  const float* Wv = (const float*)d_in[6];
  const float* bv = (const float*)d_in[7];
  const float* Wo = (const float*)d_in[8];
  const float* bo = (const float*)d_in[9];
  float* out = (float*)d_out;

  char* ws = (char*)d_ws;
  unsigned short* hbf  = (unsigned short*)(ws);               // hidden bf16; later attn_out
  unsigned short* Wbuf = (unsigned short*)(ws + 33554432);    // Wqkv bf16; later Wo
  unsigned short* QKV  = (unsigned short*)(ws + 83886080);    // [4096][6144]
  unsigned short* Vtb  = (unsigned short*)(ws + 134217728);   // [2048][2048]
  float*          biasb= (float*)(ws + 142606336);            // 6144 floats

  // 1. fused casts (hidden + Wq + Wk + Wv, one launch)
  cast4<<<2560, 256, 0, stream>>>(
      (const float4*)hs, (const float4*)Wq, (const float4*)Wk, (const float4*)Wv,
      (ushort4*)hbf, (ushort4*)Wbuf, (ushort4*)(Wbuf + 16777216), (ushort4*)(Wbuf + 20971520));
  hipMemcpyAsync(biasb, bq, 4096 * 4, hipMemcpyDeviceToDevice, stream);
  hipMemcpyAsync(biasb + 4096, bk, 1024 * 4, hipMemcpyDeviceToDevice, stream);
  hipMemcpyAsync(biasb + 5120, bv, 1024 * 4, hipMemcpyDeviceToDevice, stream);

  // 2a. Q projection + fused RoPE -> QKV cols 0..4095 (256 blocks, XCD swizzle)
  gemm256<0, 1><<<dim3(256), 512, 0, stream>>>(hbf, Wbuf, biasb, QKV, pos, LDQKV, 4096);
  // 2b. KV projection (+ fused K-RoPE on gc<1024) -> QKV cols 4096..6143 (256 blocks)
  gemm128<0, 1><<<dim3(256), 512, 0, stream>>>(hbf, Wbuf + 16777216, biasb + 4096, QKV + 4096, pos, LDQKV, 4096);

  // 3. Wo cast into Wbuf
  cast_f32_bf16<<<2048, 256, 0, stream>>>((const float4*)Wo, (ushort4*)Wbuf, 4194304);

  // 4. V transpose -> Vt[2048][2048]
  transpose_v<<<dim3(32, 128), 256, 0, stream>>>(QKV + 5120, LDQKV, Vtb);

  // 5. causal GQA flash attention (KVBLK=128, K-prefetch-under-softmax) -> hbf
  attn_kernel5<<<dim3(1024), 256, 0, stream>>>(QKV, Vtb, hbf);

  // 6. output projection -> fp32 d_out
  gemm256<1, 0><<<dim3(256), 512, 0, stream>>>(hbf, Wbuf, bo, out, nullptr, 4096, 4096);
}

// Round 19
// 495.402 us; speedup vs baseline: 1.0802x; 1.0142x over previous
//
#include <hip/hip_runtime.h>
#include <stdint.h>

typedef __bf16 bf16x8 __attribute__((ext_vector_type(8)));
typedef float f32x4 __attribute__((ext_vector_type(4)));
typedef float f32x16 __attribute__((ext_vector_type(16)));

#define S_LEN 2048
#define NKVH 8
#define HDIM 128
#define MROWS 4096        // B*S
#define LDQKV 6144        // fused QKV row stride
#define SCALE 0.08838834764831845f
#define C_LOG2 0.1275405707067851f   // SCALE * log2(e)
#define THR_RAW 62.7f                // 8 / C_LOG2
#define ROPE_L2 0.31143075889569023f // log2(1e6)/64

__device__ __forceinline__ unsigned short f2bf(float f) {
  unsigned u = __float_as_uint(f);
  u += 0x7FFFu + ((u >> 16) & 1u);
  return (unsigned short)(u >> 16);
}
__device__ __forceinline__ float bf2f(unsigned short h) {
  return __uint_as_float(((unsigned)h) << 16);
}

__device__ __forceinline__ void gload16(const unsigned short* g, unsigned short* l) {
  __builtin_amdgcn_global_load_lds(
      (__attribute__((address_space(1))) void*)(g),
      (__attribute__((address_space(3))) void*)(l), 16, 0, 0);
}

// ---------------- fused fp32->bf16 cast: hidden + Wq + Wk + Wv (one launch) ----------------
__global__ void cast4(const float4* __restrict__ s0, const float4* __restrict__ s1,
                      const float4* __restrict__ s2, const float4* __restrict__ s3,
                      ushort4* __restrict__ d0, ushort4* __restrict__ d1,
                      ushort4* __restrict__ d2, ushort4* __restrict__ d3) {
  const int b = blockIdx.x;
  const float4* s; ushort4* d; int lb;
  if (b < 1024)      { s = s0; d = d0; lb = b; }
  else if (b < 2048) { s = s1; d = d1; lb = b - 1024; }
  else if (b < 2304) { s = s2; d = d2; lb = b - 2048; }
  else               { s = s3; d = d3; lb = b - 2304; }
  int base = lb * 4096 + threadIdx.x;
#pragma unroll
  for (int i = 0; i < 16; i++) {
    float4 v = s[base + i * 256];
    ushort4 o;
    o.x = f2bf(v.x); o.y = f2bf(v.y); o.z = f2bf(v.z); o.w = f2bf(v.w);
    d[base + i * 256] = o;
  }
}

// ---------------- plain cast (Wo) ----------------
__global__ void cast_f32_bf16(const float4* __restrict__ in, ushort4* __restrict__ out, int n4) {
  int i = blockIdx.x * 256 + threadIdx.x;
  const int stride = gridDim.x * 256;
  for (; i < n4; i += stride) {
    float4 v = in[i];
    ushort4 o;
    o.x = f2bf(v.x); o.y = f2bf(v.y); o.z = f2bf(v.z); o.w = f2bf(v.w);
    out[i] = o;
  }
}

// ---------------- GEMM 256x256, BK=64, 8 waves, 8-phase schedule; XCD swizzle ----
template <int OUTF, int ROPE>
__global__ __launch_bounds__(512, 2)
void gemm256(const unsigned short* __restrict__ A,
             const unsigned short* __restrict__ Bw,
             const float* __restrict__ bias,
             void* __restrict__ C,
             const int* __restrict__ pos,
             int ldc, int K) {
  __shared__ unsigned short lds[8][8192];   // 128 KiB

  const int t = threadIdx.x;
  const int lane = t & 63;
  const int w = t >> 6;
  const int wr = w >> 2, wc = w & 3;           // 2 x 4 waves
  const int row16 = lane & 15, kgrp = lane >> 4;
  const int bid = blockIdx.x;
  const int swz = (bid & 7) * 32 + (bid >> 3);
  const int m0 = (swz >> 4) * 256, n0 = (swz & 15) * 256;

  const int riu = t >> 3;                           // 0..63
  const int col = (((t & 7) ^ (riu & 7)) << 3);     // pre-swizzled src col
  const int rB0 = (riu & 31) + ((riu >> 5) << 6);   // B qn0 row for load0
  const unsigned short* pA = A + (size_t)(m0 + riu) * K + col;
  const unsigned short* pB = Bw + (size_t)(n0 + rB0) * K + col;

#define STGU(SL, SRC)                                                       \
  {                                                                         \
    gload16((SRC), &lds[SL][t * 8]);                                        \
    gload16((SRC) + (size_t)128 * K, &lds[SL][4096 + t * 8]);               \
  }
#define RDA(SL)                                                             \
  _Pragma("unroll") for (int mi = 0; mi < 4; mi++)                          \
  _Pragma("unroll") for (int ks = 0; ks < 2; ks++)                          \
    afr[mi][ks] = *(const bf16x8*)(&lds[SL][0] + abase + mi * 1024 +        \
                                   ((((ks << 2) + kgrp) ^ sw) << 3));
#define RDB(SL, W)                                                          \
  _Pragma("unroll") for (int nj = 0; nj < 2; nj++)                          \
  _Pragma("unroll") for (int ks = 0; ks < 2; ks++)                          \
    bfr[W][nj][ks] = *(const bf16x8*)(&lds[SL][0] + bbase + nj * 1024 +     \
                                      ((((ks << 2) + kgrp) ^ sw) << 3));
#define MM(MO, NO, W)                                                       \
  __builtin_amdgcn_s_setprio(1);                                            \
  _Pragma("unroll") for (int mi = 0; mi < 4; mi++)                          \
  _Pragma("unroll") for (int nj = 0; nj < 2; nj++)                          \
  _Pragma("unroll") for (int ks = 0; ks < 2; ks++)                          \
    acc[(MO) + mi][(NO) + nj] = __builtin_amdgcn_mfma_f32_16x16x32_bf16(    \
        afr[mi][ks], bfr[W][nj][ks], acc[(MO) + mi][(NO) + nj], 0, 0, 0);   \
  __builtin_amdgcn_s_setprio(0);
#define BAR __builtin_amdgcn_s_barrier()

  const int sw = row16 & 7;
  const int abase = (wr * 64 + row16) * 64;
  const int bbase = (wc * 32 + row16) * 64;

  f32x4 acc[8][4];
#pragma unroll
  for (int i = 0; i < 8; i++)
#pragma unroll
    for (int j = 0; j < 4; j++) acc[i][j] = (f32x4){0.f, 0.f, 0.f, 0.f};

  bf16x8 afr[4][2], bfr[2][2][2];
  const int NT = K >> 6;
  const int NI = NT >> 1;

  STGU(0, pA);
  STGU(1, pB);
  STGU(2, pB + (size_t)32 * K);
  STGU(3, pA + (size_t)64 * K);
  STGU(4, pA + 64);
  STGU(5, pB + 64);
  STGU(6, pB + (size_t)32 * K + 64);
  asm volatile("s_waitcnt vmcnt(6)" ::: "memory");
  BAR;

  for (int I = 0; I < NI; ++I) {
    const size_t k1 = ((size_t)(2 * I + 1)) << 6;
    const size_t k2 = ((size_t)(2 * I + 2)) << 6;
    const size_t k3 = ((size_t)(2 * I + 3)) << 6;
    const bool s2 = (I + 1 < NI);

    RDA(0); RDB(1, 0);
    STGU(7, pA + (size_t)64 * K + k1);
    BAR;
    MM(0, 0, 0);
    BAR;
    RDB(2, 1);
    if (s2) STGU(0, pA + k2);
    BAR;
    MM(0, 2, 1);
    BAR;
    RDA(3);
    if (s2) STGU(1, pB + k2);
    BAR;
    MM(4, 2, 1);
    BAR;
    if (s2) {
      STGU(2, pB + (size_t)32 * K + k2);
      asm volatile("s_waitcnt vmcnt(6)" ::: "memory");
    } else {
      asm volatile("s_waitcnt vmcnt(0)" ::: "memory");
    }
    BAR;
    MM(4, 0, 0);
    BAR;
    RDA(4); RDB(5, 0);
    if (s2) STGU(3, pA + (size_t)64 * K + k2);
    BAR;
    MM(0, 0, 0);
    BAR;
    RDB(6, 1);
    if (s2) STGU(4, pA + k3);
    BAR;
    MM(0, 2, 1);
    BAR;
    RDA(7);
    if (s2) STGU(5, pB + k3);
    BAR;
    MM(4, 2, 1);
    BAR;
    if (s2) {
      STGU(6, pB + (size_t)32 * K + k3);
      asm volatile("s_waitcnt vmcnt(6)" ::: "memory");
    } else {
      asm volatile("s_waitcnt vmcnt(0)" ::: "memory");
    }
    BAR;
    MM(4, 0, 0);
    BAR;
  }
#undef STGU
#undef RDA
#undef RDB
#undef MM
#undef BAR

#pragma unroll
  for (int MI = 0; MI < 8; MI++) {
#pragma unroll
    for (int NJ = 0; NJ < 4; NJ++) {
      const int gr = m0 + wr * 128 + MI * 16 + kgrp * 4;
      const int gc = n0 + wc * 64 + NJ * 16 + row16;
      const float bv = bias[gc];
      if (ROPE) {
        const int hf = (gc & 127) >> 1;
        const float inv = exp2f(-(float)hf * ROPE_L2);
#pragma unroll
        for (int jj = 0; jj < 4; jj++) {
          float v = acc[MI][NJ][jj] + bv;
          float px = __shfl_xor(v, 1);
          float sn, cs;
          __sincosf((float)pos[gr + jj] * inv, &sn, &cs);
          float ov = (gc & 1) ? fmaf(v, cs, px * sn) : fmaf(v, cs, -px * sn);
          ((unsigned short*)C)[(size_t)(gr + jj) * ldc + gc] = f2bf(ov);
        }
      } else {
#pragma unroll
        for (int jj = 0; jj < 4; jj++) {
          float v = acc[MI][NJ][jj] + bv;
          if (OUTF) ((float*)C)[(size_t)(gr + jj) * ldc + gc] = v;
          else ((unsigned short*)C)[(size_t)(gr + jj) * ldc + gc] = f2bf(v);
        }
      }
    }
  }
}

// ---------------- GEMM 128x256, BK=64, 8 waves, 3-buffer ring; fused K-RoPE; XCD swizzle ----
template <int OUTF, int ROPE>
__global__ __launch_bounds__(512, 2)
void gemm128(const unsigned short* __restrict__ A,
             const unsigned short* __restrict__ Bw,
             const float* __restrict__ bias,
             void* __restrict__ C,
             const int* __restrict__ pos,
             int ldc, int K) {
  __shared__ unsigned short lds[3 * 24576];   // 144 KiB

  const int t = threadIdx.x;
  const int lane = t & 63;
  const int w = t >> 6;
  const int wr = w >> 2, wc = w & 3;           // 2(M) x 4(N) waves -> 64x64 each
  const int row16 = lane & 15, kgrp = lane >> 4;
  const int bid = blockIdx.x;
  const int swz = (bid & 7) * 32 + (bid >> 3);
  const int m0 = (swz >> 3) * 128, n0 = (swz & 7) * 256;

  const int riu = t >> 3;                           // 0..63
  const int col = (((t & 7) ^ (riu & 7)) << 3);     // pre-swizzled src col
  const unsigned short* pA = A + (size_t)(m0 + riu) * K + col;
  const unsigned short* pB = Bw + (size_t)(n0 + riu) * K + col;

#define STG6(bo_, kk_)                                                      \
  {                                                                         \
    gload16(pA + (kk_), &lds[(bo_) + t * 8]);                               \
    gload16(pA + (size_t)64 * K + (kk_), &lds[(bo_) + 4096 + t * 8]);       \
    gload16(pB + (kk_), &lds[(bo_) + 8192 + t * 8]);                        \
    gload16(pB + (size_t)64 * K + (kk_), &lds[(bo_) + 12288 + t * 8]);      \
    gload16(pB + (size_t)128 * K + (kk_), &lds[(bo_) + 16384 + t * 8]);     \
    gload16(pB + (size_t)192 * K + (kk_), &lds[(bo_) + 20480 + t * 8]);     \
  }

  const int sw = row16 & 7;
  const int abase = (wr * 64 + row16) * 64;           // within A unit
  const int bbase = 8192 + (wc * 64 + row16) * 64;    // within buffer (B at +8192)

  f32x4 acc[4][4];
#pragma unroll
  for (int i = 0; i < 4; i++)
#pragma unroll
    for (int j = 0; j < 4; j++) acc[i][j] = (f32x4){0.f, 0.f, 0.f, 0.f};

  bf16x8 afr[4][2], bfr[4][2];
  const int NT = K >> 6;

  STG6(0, 0);
  STG6(24576, 64);

  int rbc = 0;          // T%3 buffer offset index
  int rbs = 2;          // (T+2)%3
  for (int T = 0; T < NT; ++T) {
    if (T < NT - 1) { asm volatile("s_waitcnt vmcnt(6)\n\ts_barrier" ::: "memory"); }
    else            { asm volatile("s_waitcnt vmcnt(0)\n\ts_barrier" ::: "memory"); }
    if (T + 2 < NT) STG6(rbs * 24576, (size_t)(T + 2) << 6);
    const unsigned short* Lc = &lds[rbc * 24576];

#pragma unroll
    for (int mi = 0; mi < 4; mi++)
#pragma unroll
      for (int ks = 0; ks < 2; ks++)
        afr[mi][ks] = *(const bf16x8*)(Lc + abase + mi * 1024 + ((((ks << 2) + kgrp) ^ sw) << 3));
#pragma unroll
    for (int nj = 0; nj < 4; nj++)
#pragma unroll
      for (int ks = 0; ks < 2; ks++)
        bfr[nj][ks] = *(const bf16x8*)(Lc + bbase + nj * 1024 + ((((ks << 2) + kgrp) ^ sw) << 3));

    __builtin_amdgcn_s_setprio(1);
#pragma unroll
    for (int mi = 0; mi < 4; mi++)
#pragma unroll
      for (int nj = 0; nj < 4; nj++)
#pragma unroll
        for (int ks = 0; ks < 2; ks++)
          acc[mi][nj] = __builtin_amdgcn_mfma_f32_16x16x32_bf16(afr[mi][ks], bfr[nj][ks], acc[mi][nj], 0, 0, 0);
    __builtin_amdgcn_s_setprio(0);

    rbc++; if (rbc == 3) rbc = 0;
    rbs++; if (rbs == 3) rbs = 0;
  }
#undef STG6

#pragma unroll
  for (int MI = 0; MI < 4; MI++) {
#pragma unroll
    for (int NJ = 0; NJ < 4; NJ++) {
      const int gr = m0 + wr * 64 + MI * 16 + kgrp * 4;
      const int gc = n0 + wc * 64 + NJ * 16 + row16;
      const float bv = bias[gc];
      if (ROPE && gc < 1024) {          // K region (uniform per block: 256 | 1024)
        const int hf = (gc & 127) >> 1;
        const float inv = exp2f(-(float)hf * ROPE_L2);
#pragma unroll
        for (int jj = 0; jj < 4; jj++) {
          float v = acc[MI][NJ][jj] + bv;
          float px = __shfl_xor(v, 1);
          float sn, cs;
          __sincosf((float)pos[gr + jj] * inv, &sn, &cs);
          float ov = (gc & 1) ? fmaf(v, cs, px * sn) : fmaf(v, cs, -px * sn);
          ((unsigned short*)C)[(size_t)(gr + jj) * ldc + gc] = f2bf(ov);
        }
      } else {
#pragma unroll
        for (int jj = 0; jj < 4; jj++) {
          float v = acc[MI][NJ][jj] + bv;
          if (OUTF) ((float*)C)[(size_t)(gr + jj) * ldc + gc] = v;
          else ((unsigned short*)C)[(size_t)(gr + jj) * ldc + gc] = f2bf(v);
        }
      }
    }
  }
}

// ---------------- V transpose: V[m, n] (stride ldv) -> Vt[b*1024 + n][m % 2048] ----------------
__global__ void transpose_v(const unsigned short* __restrict__ V, int ldv,
                            unsigned short* __restrict__ Vt) {
  __shared__ unsigned short tile[32][40];
  const int t = threadIdx.x;
  const int n0 = blockIdx.x * 32;   // V col (0..1023)
  const int m0 = blockIdx.y * 32;   // V row (0..4095)
  const int r = t >> 3;
  const int c = (t & 7) << 2;
  const unsigned short* src = V + (size_t)(m0 + r) * ldv + n0 + c;
  ushort4 d = *(const ushort4*)src;
  tile[r][c] = d.x; tile[r][c + 1] = d.y; tile[r][c + 2] = d.z; tile[r][c + 3] = d.w;
  __syncthreads();
  const int b = m0 >> 11;
  unsigned short* dst = Vt + (size_t)(b * 1024 + n0 + r) * 2048 + (m0 & 2047) + c;
  ushort4 o;
  o.x = tile[c][r]; o.y = tile[c + 1][r]; o.z = tile[c + 2][r]; o.w = tile[c + 3][r];
  *(ushort4*)dst = o;
}

// ---------------- causal GQA flash attention, KVBLK=128, split-wait K/V ----------------
// Best-measured attention (round 16: 130.5-131.5 us). Issue K's 8 loads then
// V's 8; vmcnt(8)+barrier -> K landed -> QK^T + softmax + P-conversion run
// WHILE V is still in flight; vmcnt(0)+barrier -> PV. Barriers uniform.
// Tile-max uses fmaxf triples so clang fuses v_max3_f32 (T17) — identical math.
__global__ __launch_bounds__(256, 2)
void attn_kernel4(const unsigned short* __restrict__ QKV,
                  const unsigned short* __restrict__ Vt,
                  unsigned short* __restrict__ O) {
  __shared__ unsigned short sK[2 * 128 * 64];   // 32 KB
  __shared__ unsigned short sV[2 * 128 * 64];   // 32 KB

  const int t = threadIdx.x;
  const int lane = t & 63;
  const int w = t >> 6;                   // 0..3
  const int l31 = lane & 31;
  const int hi = lane >> 5;
  const int bid = blockIdx.x;
  const int g = bid >> 6, bh = bid & 63;
  const int qt = (g < 8) ? (15 - g) : (g - 8);
  const int b = bh >> 5, h = bh & 31;
  const int kh = h >> 2;                  // n_rep = 4 (repeat_interleave)
  const int q0 = qt << 7;                 // 128-row q-subtile
  const int qw = q0 + w * 32;
  const int qg = qw + l31;                // this lane's q row (softmax state owner)

  const int ntiles = qt + 1;              // KVBLK = 128
  const int myTiles = (qw + 159) >> 7;    // ceil((qw+32)/128)

  const int r5 = t >> 3;                  // 0..31
  const int psw = ((t & 7) ^ (r5 & 7)) << 3;    // pre-XOR'd col within 64-us half
  const unsigned short* Kp = QKV + (size_t)(b * S_LEN) * LDQKV + 4096 + kh * HDIM;
  const unsigned short* Vp = Vt + (size_t)(b * 1024 + kh * HDIM) * 2048;
  const unsigned short* KpA = Kp + (size_t)r5 * LDQKV + psw;
  const unsigned short* VpA = Vp + (size_t)r5 * 2048 + psw;

#define STAGE_K(kv0m)                                                          \
  {                                                                            \
    _Pragma("unroll")                                                          \
    for (int p = 0; p < 8; p++)                                                \
      gload16(KpA + (size_t)((kv0m) + ((p & 3) << 5)) * LDQKV + ((p >> 2) << 6), \
              &sK[p * 2048 + t * 8]);                                          \
  }
#define STAGE_V(kv0m)                                                          \
  {                                                                            \
    _Pragma("unroll")                                                          \
    for (int p = 0; p < 8; p++)                                                \
      gload16(VpA + (size_t)((p & 3) << 5) * 2048 + (kv0m) + ((p >> 2) << 6),  \
              &sV[p * 2048 + t * 8]);                                          \
  }

  bf16x8 qf[8];
  {
    const unsigned short* qb = QKV + (size_t)(b * S_LEN + qw + l31) * LDQKV + h * HDIM + hi * 8;
#pragma unroll
    for (int kd = 0; kd < 8; kd++) qf[kd] = *(const bf16x8*)(qb + kd * 16);
  }

  f32x16 o[4];
#pragma unroll
  for (int nt = 0; nt < 4; nt++)
#pragma unroll
    for (int r = 0; r < 16; r++) o[nt][r] = 0.f;
  float m = -1e30f, lsum = 0.f;

  const int rw7 = (l31 & 7) << 4;
  const int kswz = (hi << 4) ^ rw7;
  const int rbase = l31 << 6;             // row base within a 128x64 half

  for (int it = 0; it < ntiles; ++it) {
    STAGE_K(it << 7);
    STAGE_V(it << 7);
    asm volatile("s_waitcnt vmcnt(8)" ::: "memory");   // K landed (V in flight)
    __builtin_amdgcn_s_barrier();

    const bool act = (it < myTiles);
    bf16x8 pa[8];

    if (act) {
      const int kv0 = it << 7;

      f32x16 st[4];
#pragma unroll
      for (int r = 0; r < 16; r++) { st[0][r] = 0.f; st[1][r] = 0.f; st[2][r] = 0.f; st[3][r] = 0.f; }
      __builtin_amdgcn_s_setprio(1);
#pragma unroll
      for (int kd = 0; kd < 8; kd++) {
        const int koff = ((kd >> 2) << 13) + ((((kd & 3) << 5) ^ kswz) >> 1);
        bf16x8 k0 = *(const bf16x8*)(sK + koff + rbase);
        bf16x8 k1 = *(const bf16x8*)(sK + koff + rbase + 2048);
        bf16x8 k2 = *(const bf16x8*)(sK + koff + rbase + 4096);
        bf16x8 k3 = *(const bf16x8*)(sK + koff + rbase + 6144);
        st[0] = __builtin_amdgcn_mfma_f32_32x32x16_bf16(k0, qf[kd], st[0], 0, 0, 0);
        st[1] = __builtin_amdgcn_mfma_f32_32x32x16_bf16(k1, qf[kd], st[1], 0, 0, 0);
        st[2] = __builtin_amdgcn_mfma_f32_32x32x16_bf16(k2, qf[kd], st[2], 0, 0, 0);
        st[3] = __builtin_amdgcn_mfma_f32_32x32x16_bf16(k3, qf[kd], st[3], 0, 0, 0);
      }
      __builtin_amdgcn_s_setprio(0);

      if (it == myTiles - 1) {
#pragma unroll
        for (int s2 = 0; s2 < 4; s2++)
#pragma unroll
          for (int r = 0; r < 16; r++) {
            const int kvg = kv0 + s2 * 32 + (r & 3) + 8 * (r >> 2) + 4 * hi;
            if (kvg > qg) st[s2][r] = -1e30f;
          }
      }

      // ---- tile max: v_max3-friendly triples (identical max over 64 values) ----
      float mx[8];
#pragma unroll
      for (int r = 0; r < 8; r++) {
        const float a3 = fmaxf(fmaxf(st[0][r], st[0][r + 8]), st[1][r]);
        const float b3 = fmaxf(fmaxf(st[1][r + 8], st[2][r]), st[2][r + 8]);
        const float c3 = fmaxf(fmaxf(st[3][r], st[3][r + 8]), a3);
        mx[r] = fmaxf(b3, c3);
      }
      const float u0 = fmaxf(fmaxf(mx[0], mx[1]), mx[2]);
      const float u1 = fmaxf(fmaxf(mx[3], mx[4]), mx[5]);
      const float u2 = fmaxf(fmaxf(mx[6], mx[7]), u0);
      float tmax = fmaxf(u1, u2);
      tmax = fmaxf(tmax, __shfl_xor(tmax, 32));

      if (!__all(tmax <= m + THR_RAW)) {
        const float mnew = fmaxf(m, tmax);
        const float corr = exp2f((m - mnew) * C_LOG2);
        lsum *= corr;
#pragma unroll
        for (int r = 0; r < 16; r++) {
          const int src = (r & 3) + 8 * (r >> 2) + 4 * hi;
          const float cr = __shfl(corr, src);
#pragma unroll
          for (int nt = 0; nt < 4; nt++) o[nt][r] *= cr;
        }
        m = mnew;
      }
      const float mC = m * C_LOG2;

#pragma unroll
      for (int s2 = 0; s2 < 4; s2++)
#pragma unroll
        for (int r = 0; r < 16; r++) st[s2][r] = exp2f(fmaf(st[s2][r], C_LOG2, -mC));
      float sm[8];
#pragma unroll
      for (int r = 0; r < 8; r++)
        sm[r] = ((st[0][r] + st[0][r + 8]) + (st[1][r] + st[1][r + 8])) +
                ((st[2][r] + st[2][r + 8]) + (st[3][r] + st[3][r + 8]));
#pragma unroll
      for (int d = 4; d >= 1; d >>= 1)
#pragma unroll
        for (int r = 0; r < d; r++) sm[r] += sm[r + d];
      float tsum = sm[0] + __shfl_xor(sm[0], 32);
      lsum += tsum;

#pragma unroll
      for (int s2 = 0; s2 < 4; s2++) {
        unsigned pw[8];
#pragma unroll
        for (int i = 0; i < 8; i++)
          asm("v_cvt_pk_bf16_f32 %0, %1, %2" : "=v"(pw[i]) : "v"(st[s2][2 * i]), "v"(st[s2][2 * i + 1]));
        const unsigned y0 = hi ? pw[0] : pw[2];
        const unsigned y1 = hi ? pw[1] : pw[3];
        const unsigned y2 = hi ? pw[4] : pw[6];
        const unsigned y3 = hi ? pw[5] : pw[7];
        const unsigned x0 = (unsigned)__shfl_xor((int)y0, 32);
        const unsigned x1 = (unsigned)__shfl_xor((int)y1, 32);
        const unsigned x2 = (unsigned)__shfl_xor((int)y2, 32);
        const unsigned x3 = (unsigned)__shfl_xor((int)y3, 32);
        union { unsigned u[4]; bf16x8 v; } u0v, u1v;
        u0v.u[0] = hi ? x0 : pw[0];
        u0v.u[1] = hi ? x1 : pw[1];
        u0v.u[2] = hi ? pw[2] : x0;
        u0v.u[3] = hi ? pw[3] : x1;
        u1v.u[0] = hi ? x2 : pw[4];
        u1v.u[1] = hi ? x3 : pw[5];
        u1v.u[2] = hi ? pw[6] : x2;
        u1v.u[3] = hi ? pw[7] : x3;
        pa[2 * s2] = u0v.v; pa[2 * s2 + 1] = u1v.v;
      }
    }

    asm volatile("s_waitcnt vmcnt(0)" ::: "memory");   // V landed
    __builtin_amdgcn_s_barrier();

    if (act) {
      __builtin_amdgcn_s_setprio(1);
#pragma unroll
      for (int nt = 0; nt < 4; nt++) {
        const unsigned short* vr = sV + nt * 2048 + rbase;
#pragma unroll
        for (int ks = 0; ks < 8; ks++) {
          bf16x8 vb = *(const bf16x8*)(vr + ((ks >> 2) << 13) + ((((ks & 3) << 5) ^ kswz) >> 1));
          o[nt] = __builtin_amdgcn_mfma_f32_32x32x16_bf16(pa[ks], vb, o[nt], 0, 0, 0);
        }
      }
      __builtin_amdgcn_s_setprio(0);
    }

    __builtin_amdgcn_s_barrier();   // seals sK/sV before next STAGE
  }

  const float linv = 1.0f / lsum;
#pragma unroll
  for (int r = 0; r < 16; r++) {
    const int qr = (r & 3) + 8 * (r >> 2) + 4 * hi;
    const float lr = __shfl(linv, qr);
    unsigned short* orow = O + (size_t)(b * S_LEN + qw + qr) * 4096 + h * HDIM + l31;
#pragma unroll
    for (int nt = 0; nt < 4; nt++) orow[nt * 32] = f2bf(o[nt][r] * lr);
  }
#undef STAGE_K
#undef STAGE_V
}

// ---------------- launch ----------------
extern "C" void kernel_launch(void* const* d_in, const int* in_sizes, int n_in,
                              void* d_out, int out_size, void* d_ws, size_t ws_size,
                              hipStream_t stream) {
  const float* hs = (const float*)d_in[0];
  const int*  pos = (const int*)d_in[1];
  const float* Wq = (const float*)d_in[2];
  const float* bq = (const float*)d_in[3];
  const float* Wk = (const float*)d_in[4];
  const float* bk = (const float*)d_in[5];
  const float* Wv = (const float*)d_in[6];
  const float* bv = (const float*)d_in[7];
  const float* Wo = (const float*)d_in[8];
  const float* bo = (const float*)d_in[9];
  float* out = (float*)d_out;

  char* ws = (char*)d_ws;
  unsigned short* hbf  = (unsigned short*)(ws);               // hidden bf16; later attn_out
  unsigned short* Wbuf = (unsigned short*)(ws + 33554432);    // Wqkv bf16; later Wo
  unsigned short* QKV  = (unsigned short*)(ws + 83886080);    // [4096][6144]
  unsigned short* Vtb  = (unsigned short*)(ws + 134217728);   // [2048][2048]
  float*          biasb= (float*)(ws + 142606336);            // 6144 floats

  // 1. fused casts (hidden + Wq + Wk + Wv, one launch)
  cast4<<<2560, 256, 0, stream>>>(
      (const float4*)hs, (const float4*)Wq, (const float4*)Wk, (const float4*)Wv,
      (ushort4*)hbf, (ushort4*)Wbuf, (ushort4*)(Wbuf + 16777216), (ushort4*)(Wbuf + 20971520));
  hipMemcpyAsync(biasb, bq, 4096 * 4, hipMemcpyDeviceToDevice, stream);
  hipMemcpyAsync(biasb + 4096, bk, 1024 * 4, hipMemcpyDeviceToDevice, stream);
  hipMemcpyAsync(biasb + 5120, bv, 1024 * 4, hipMemcpyDeviceToDevice, stream);

  // 2a. Q projection + fused RoPE -> QKV cols 0..4095 (256 blocks, XCD swizzle)
  gemm256<0, 1><<<dim3(256), 512, 0, stream>>>(hbf, Wbuf, biasb, QKV, pos, LDQKV, 4096);
  // 2b. KV projection (+ fused K-RoPE on gc<1024) -> QKV cols 4096..6143 (256 blocks)
  gemm128<0, 1><<<dim3(256), 512, 0, stream>>>(hbf, Wbuf + 16777216, biasb + 4096, QKV + 4096, pos, LDQKV, 4096);

  // 3. Wo cast into Wbuf
  cast_f32_bf16<<<2048, 256, 0, stream>>>((const float4*)Wo, (ushort4*)Wbuf, 4194304);

  // 4. V transpose -> Vt[2048][2048]
  transpose_v<<<dim3(32, 128), 256, 0, stream>>>(QKV + 5120, LDQKV, Vtb);

  // 5. causal GQA flash attention (KVBLK=128, split-wait K/V) -> hbf
  attn_kernel4<<<dim3(1024), 256, 0, stream>>>(QKV, Vtb, hbf);

  // 6. output projection -> fp32 d_out
  gemm256<1, 0><<<dim3(256), 512, 0, stream>>>(hbf, Wbuf, bo, out, nullptr, 4096, 4096);
}